// Round 5
// baseline (265.025 us; speedup 1.0000x reference)
//
#include <hip/hip_runtime.h>
#include <hip/hip_bf16.h>

#define GSZ 36
static const int NX  = 16 * 32 * 224 * 224;     // 25,690,112
static const int NX4 = NX / 4;                  // 6,422,528
static const int NW  = 32 * 32 * 3 * 3;         // 9,216
static const int GXN = (NX + GSZ - 1) / GSZ;    // 713,615
static const int HWp = 224 * 224;               // 50,176
static const int NBOUND = NX / 448;             // 57,344 flat 448-chunks

typedef short bf16x8 __attribute__((ext_vector_type(8)));
typedef float f32x4  __attribute__((ext_vector_type(4)));

// floor(n/36), exact for 0 <= n < 2^31
__device__ __forceinline__ unsigned div36(unsigned n) {
    return (unsigned)(((unsigned long long)n * 954437177ull) >> 35);
}
// scale = 2^(floor(log2 m) - 7) via exponent field (m normal > 0)
__device__ __forceinline__ float scale_from_max(float m) {
    int e = (int)((__float_as_uint(m) >> 23) & 0xffu) - 127;
    return __uint_as_float((unsigned)(e + 120) << 23);
}
// 1/scale for power-of-two scale
__device__ __forceinline__ float inv_from_scale(float s) {
    return __uint_as_float(0x7F000000u - __float_as_uint(s));
}
__device__ __forceinline__ unsigned short f2bf(float f) {
    return (unsigned short)(__float_as_uint(f) >> 16);  // truncation: binade-preserving
}
__device__ __forceinline__ float bf2f(unsigned short u) {
    return __uint_as_float(((unsigned)u) << 16);
}

// ---------- quantize w + layout to wt[s][co][ci] bf16 (unchanged) ----------
__global__ void k_quant_wt(const float* __restrict__ w, unsigned short* __restrict__ wt) {
    int g = threadIdx.x;
    int base = g * GSZ;
    float v[GSZ];
    const float4* p = reinterpret_cast<const float4*>(w + base);
    #pragma unroll
    for (int i = 0; i < 9; ++i) {
        float4 t = p[i];
        v[4*i+0] = t.x; v[4*i+1] = t.y; v[4*i+2] = t.z; v[4*i+3] = t.w;
    }
    float m = 0.0f;
    #pragma unroll
    for (int i = 0; i < GSZ; ++i) m = fmaxf(m, fabsf(v[i]));
    if (m > 0.0f) {
        float s = scale_from_max(m), inv = inv_from_scale(s);
        #pragma unroll
        for (int i = 0; i < GSZ; ++i) v[i] = rintf(v[i] * inv) * s;
    }
    #pragma unroll
    for (int i = 0; i < GSZ; ++i) {
        int f = base + i;
        int co = f / 288, rem = f - co * 288;
        int ci = rem / 9, s = rem - ci * 9;
        wt[s * 1024 + co * 32 + ci] = f2bf(v[i]);
    }
}

// ---------- fused x: BFP-quantize + NCHW->NHWC (unchanged from round 4) ----------
#define TSTR 452
__global__ __launch_bounds__(256, 4) void k_quant_x_fused(const float* __restrict__ x,
                                                          unsigned short* __restrict__ xt) {
    __shared__ unsigned short tile[32 * TSTR];
    __shared__ float scl[32 * 14];
    __shared__ int rem36s[32], offs[32];

    int t = threadIdx.x;
    int b = blockIdx.y, hp = blockIdx.x;
    int F0 = (b * 32) * HWp + hp * 448;

    if (t < 32) {
        int F = F0 + t * HWp;
        int r = F - 36 * (int)div36((unsigned)F);
        rem36s[t] = r;
        offs[t] = (F - r) & 3;
    }
    for (int i = t; i < 448; i += 256) ((unsigned*)scl)[i] = 0u;
    __syncthreads();

    for (int j = 0; j < 16; ++j) {
        int idx = t + 256 * j;
        int ci = idx >> 7, c4 = idx & 127;
        int off = offs[ci];
        int base4 = F0 + ci * HWp - rem36s[ci] - off;
        int f4 = (base4 >> 2) + c4;
        float4 v = make_float4(0.f, 0.f, 0.f, 0.f);
        if ((unsigned)f4 < (unsigned)NX4)
            v = reinterpret_cast<const float4*>(x)[f4];
        int rel0 = 4 * c4 - off;
        int r0c = rel0 > 0 ? rel0 : 0;
        int gia = (int)div36((unsigned)r0c);
        int bnd = 36 * gia + 36;
        float av[4] = {fabsf(v.x), fabsf(v.y), fabsf(v.z), fabsf(v.w)};
        float ma = 0.f, mb = 0.f;
        #pragma unroll
        for (int k = 0; k < 4; ++k) {
            int rel = rel0 + k;
            float a = ((unsigned)rel < 504u) ? av[k] : 0.f;
            if (rel < bnd) ma = fmaxf(ma, a); else mb = fmaxf(mb, a);
        }
        if (ma > 0.f) atomicMax((unsigned*)&scl[ci * 14 + gia], __float_as_uint(ma));
        if (mb > 0.f) atomicMax((unsigned*)&scl[ci * 14 + gia + 1], __float_as_uint(mb));
    }
    __syncthreads();
    for (int i = t; i < 448; i += 256)
        scl[i] = scale_from_max(__uint_as_float(((unsigned*)scl)[i]));
    __syncthreads();

    for (int j = 0; j < 14; ++j) {
        int eidx = t + 256 * j;
        int ci = ((eidx >> 4) * 293) >> 11;
        int c4 = eidx - ci * 112;
        float4 v = reinterpret_cast<const float4*>(x)[((F0 + ci * HWp) >> 2) + c4];
        int rbase = rem36s[ci] + 4 * c4;
        int gi0 = (int)div36((unsigned)rbase);
        int rr = rbase - 36 * gi0;
        float vv[4] = {v.x, v.y, v.z, v.w};
        unsigned short qb[4];
        #pragma unroll
        for (int k = 0; k < 4; ++k) {
            int gi = gi0 + ((rr + k) >= 36 ? 1 : 0);
            float s = scl[ci * 14 + gi];
            qb[k] = f2bf(rintf(vv[k] * inv_from_scale(s)) * s);
        }
        uint2 o;
        o.x = (unsigned)qb[0] | ((unsigned)qb[1] << 16);
        o.y = (unsigned)qb[2] | ((unsigned)qb[3] << 16);
        *reinterpret_cast<uint2*>(&tile[ci * TSTR + 4 * c4]) = o;
    }
    __syncthreads();

    unsigned short* ob = xt + ((size_t)b * HWp + hp * 448) * 32;
    for (int j = 0; j < 7; ++j) {
        int qd = t + 256 * j;
        int px = qd >> 2;
        int c0 = (qd & 3) * 8;
        unsigned uu[4];
        #pragma unroll
        for (int p = 0; p < 4; ++p) {
            unsigned short lo = tile[(c0 + 2 * p) * TSTR + px];
            unsigned short hi = tile[(c0 + 2 * p + 1) * TSTR + px];
            uu[p] = (unsigned)lo | ((unsigned)hi << 16);
        }
        *reinterpret_cast<uint4*>(ob + (size_t)px * 32 + c0) =
            make_uint4(uu[0], uu[1], uu[2], uu[3]);
    }
}

// ---------- fused MFMA conv + bias + out-BFP-quantize ----------
// Block: 2 rows x 224 w x 32 co for one b (512 thr). Per-co flat span = 448,
// so all block edges are multiples of 448. Interior 36-groups quantized here
// (scale via binade-exact bf16-trunc LDS tile); straddle groups written RAW
// and finished by k_fixup. Wave = (row, co-half, w-half): acc 7x4 f32/lane.
__global__ __launch_bounds__(512, 4) void k_conv_fused(const unsigned short* __restrict__ xt,
                                                       const unsigned short* __restrict__ wt,
                                                       const float* __restrict__ bias,
                                                       float* __restrict__ out) {
    // halo: 4 rows x 226 px x (32ci + 4 pad) shorts = 72,320 B; reused after
    // MFMA as obuf[32co][448] bf16 (28,672 B) + scl[32][12] f32 (1,536 B).
    __shared__ __align__(16) unsigned short smem[4 * 226 * 40];

    int tid  = threadIdx.x;
    int lane = tid & 63;
    int wid  = tid >> 6;
    int j = blockIdx.x;           // h-chunk (2 rows)
    int b = blockIdx.y;
    int h0 = j * 2;

    // --- stage 4x226 halo, all 32 ci, from NHWC (full 64B/px lines) ---
    const unsigned short* xb = xt + (size_t)b * HWp * 32;
    #pragma unroll
    for (int it = 0; it < 8; ++it) {
        int q = tid + it * 512;
        if (q < 3616) {                       // 4*226*4 16B-chunks
            int r = q / 904, rem = q - r * 904;
            int px = rem >> 2, c = rem & 3;
            int gh = h0 - 1 + r, gw = px - 1;
            uint4 val = make_uint4(0u, 0u, 0u, 0u);
            if ((unsigned)gh < 224u && (unsigned)gw < 224u)
                val = *reinterpret_cast<const uint4*>(xb + ((size_t)(gh * 224 + gw)) * 32 + c * 8);
            *reinterpret_cast<uint4*>(&smem[(r * 226 + px) * 40 + c * 8]) = val;
        }
    }

    int row = wid >> 2, cohalf = (wid >> 1) & 1, phalf = wid & 1;
    int m = lane & 15, kg = lane >> 4;
    int m4 = kg << 2;

    // weight fragments for this wave's co-half (A-operand: m=co, k=ci)
    bf16x8 Wf[9];
    #pragma unroll
    for (int s = 0; s < 9; ++s)
        Wf[s] = *reinterpret_cast<const bf16x8*>(
            wt + s * 1024 + (cohalf * 16 + m) * 32 + kg * 8);

    // acc init = bias; D row = co = cohalf*16 + m4 + reg, col = px = lane&15
    f32x4 binit;
    #pragma unroll
    for (int r4 = 0; r4 < 4; ++r4) binit[r4] = bias[cohalf * 16 + m4 + r4];
    f32x4 acc[7];
    #pragma unroll
    for (int g = 0; g < 7; ++g) acc[g] = binit;

    __syncthreads();

    // --- 9 shifts x 7 px-groups ---
    #pragma unroll
    for (int s = 0; s < 9; ++s) {
        int kh = s / 3, kw = s - kh * 3;
        int rbase = (row + kh) * 226;
        #pragma unroll
        for (int g = 0; g < 7; ++g) {
            int px = phalf * 112 + g * 16 + m + kw;   // halo px (left pad 1)
            bf16x8 X = *reinterpret_cast<const bf16x8*>(&smem[(rbase + px) * 40 + kg * 8]);
            acc[g] = __builtin_amdgcn_mfma_f32_16x16x32_bf16(Wf[s], X, acc[g], 0, 0, 0);
        }
    }

    __syncthreads();   // halo dead; reuse LDS

    unsigned short* obuf = smem;                     // [32co][448] bf16
    float* scl = reinterpret_cast<float*>(smem + 14336);  // [32co][12]

    // --- dump acc as bf16 (binade-exact for maxabs) ---
    #pragma unroll
    for (int g = 0; g < 7; ++g) {
        int rp = row * 224 + phalf * 112 + g * 16 + m;   // local flat in [0,448)
        #pragma unroll
        for (int r4 = 0; r4 < 4; ++r4) {
            int co = cohalf * 16 + m4 + r4;
            obuf[co * 448 + rp] = f2bf(acc[g][r4]);
        }
    }
    __syncthreads();

    // --- per-group scales (interior groups only) ---
    if (tid < 384) {
        int co = tid / 12, tt = tid - 12 * (tid / 12);
        int M = 112 * (b * 32 + co) + j;                 // flat 448-chunk index
        int s36 = (16 * M) % 36;
        int head = (36 - s36) % 36;
        int ninter = (448 - head) / 36;
        if (tt < ninter) {
            int base = co * 448 + head + 36 * tt;
            float mx = 0.f;
            #pragma unroll
            for (int k = 0; k < 36; ++k) mx = fmaxf(mx, fabsf(bf2f(obuf[base + k])));
            scl[co * 12 + tt] = (mx > 0.f) ? scale_from_max(mx) : 0.f;
        }
    }
    __syncthreads();

    // --- quantize exact f32 acc from registers, store (64B-coalesced) ---
    int head4[4], tail4[4], co4[4];
    #pragma unroll
    for (int r4 = 0; r4 < 4; ++r4) {
        int co = cohalf * 16 + m4 + r4;
        co4[r4] = co;
        int M = 112 * (b * 32 + co) + j;
        int s36 = (16 * M) % 36;
        int head = (36 - s36) % 36;
        head4[r4] = head;
        tail4[r4] = head + 36 * ((448 - head) / 36);
    }
    #pragma unroll
    for (int g = 0; g < 7; ++g) {
        int wl = phalf * 112 + g * 16 + m;
        int rp = row * 224 + wl;
        #pragma unroll
        for (int r4 = 0; r4 < 4; ++r4) {
            float v = acc[g][r4];
            if (rp >= head4[r4] && rp < tail4[r4]) {
                int t36 = (rp - head4[r4]) / 36;
                float s = scl[co4[r4] * 12 + t36];
                if (s != 0.f) v = rintf(v * inv_from_scale(s)) * s;
            }
            out[((size_t)(b * 32 + co4[r4]) * 224 + (h0 + row)) * 224 + wl] = v;
        }
    }
}

// ---------- fixup: quantize groups straddling 448-chunk edges ----------
// Wave per edge m in [1, NBOUND); edge cuts a group iff m % 9 != 0.
__global__ __launch_bounds__(256) void k_fixup(float* __restrict__ out) {
    int gw = (int)((blockIdx.x * 256 + threadIdx.x) >> 6);
    int lane = threadIdx.x & 63;
    int mIdx = gw + 1;
    if (mIdx >= NBOUND) return;
    if (mIdx % 9 == 0) return;                 // aligned edge, no straddle
    int f = 448 * mIdx;                        // < 2^31
    int base = 36 * (int)div36((unsigned)f);   // group containing the edge (all raw)
    float v = 0.f;
    if (lane < 36) v = out[base + lane];
    float a = fabsf(v);
    #pragma unroll
    for (int d = 1; d < 64; d <<= 1) a = fmaxf(a, __shfl_xor(a, d));
    if (lane < 36 && a > 0.f) {
        float s = scale_from_max(a);
        out[base + lane] = rintf(v * inv_from_scale(s)) * s;
    }
}

extern "C" void kernel_launch(void* const* d_in, const int* in_sizes, int n_in,
                              void* d_out, int out_size, void* d_ws, size_t ws_size,
                              hipStream_t stream) {
    (void)in_sizes; (void)n_in; (void)out_size; (void)ws_size;
    const float* x    = (const float*)d_in[0];
    const float* w    = (const float*)d_in[1];
    const float* bias = (const float*)d_in[2];
    float* out        = (float*)d_out;

    unsigned short* xt = (unsigned short*)d_ws;   // NX bf16 NHWC
    unsigned short* wt = xt + NX;                 // 9,216 bf16

    k_quant_wt<<<1, 256, 0, stream>>>(w, wt);
    k_quant_x_fused<<<dim3(112, 16), 256, 0, stream>>>(x, xt);
    k_conv_fused<<<dim3(112, 16), 512, 0, stream>>>(xt, wt, bias, out);
    k_fixup<<<(NBOUND - 1 + 3) / 4, 256, 0, stream>>>(out);
}